// Round 13
// baseline (488.721 us; speedup 1.0000x reference)
//
#include <hip/hip_runtime.h>

#define NAGENTS 8
#define NM 128          // NAGENTS*MITEMS
#define MENU 256
#define SFULL 257       // MENU + null entry

typedef float f32x4 __attribute__((ext_vector_type(4)));

// Raw barrier: wait LDS ops only (no vmcnt drain — copy-out stores and any
// in-flight loads keep flying across phases).
#define BAR() asm volatile("s_waitcnt lgkmcnt(0)\n\ts_barrier" ::: "memory")

__device__ __forceinline__ float wredmax(float v) {
#pragma unroll
    for (int o = 32; o; o >>= 1) v = fmaxf(v, __shfl_xor(v, o));
    return v;
}
__device__ __forceinline__ float wredsum(float v) {
#pragma unroll
    for (int o = 32; o; o >>= 1) v += __shfl_xor(v, o);
    return v;
}

// 256 threads/block, one auction per block, 8 blocks/CU (32 waves/CU).
// Payload streamed ONCE with PLAIN cached float4 loads/stores (R8 proved
// nontemporal causes 2x write amplification on gfx950). Batched 8 loads ->
// 8 stores -> compute for deep per-wave load pipelining. Online-softmax
// folds item_allocation into the single pass.
__global__ __launch_bounds__(256, 8) void cama_kernel(
    const float* __restrict__ bids,   // B,8,16
    const float* __restrict__ allocs, // B,256,8,16
    const float* __restrict__ wvec,   // B,8
    const float* __restrict__ bvec,   // B,256
    const float* __restrict__ tempp,  // 1
    float* __restrict__ out, int Bsz)
{
    __shared__ float lds_pwT[NAGENTS * MENU];        // 8KB, [n][s^(n<<2)]
    __shared__ float lds_tot[MENU];                  // 1KB
    __shared__ float lds_bb[MENU];                   // 1KB
    __shared__ float lds_ch[SFULL];
    __shared__ __align__(16) float4 lds_accs[4][32]; // 2KB online-acc merge
    __shared__ __align__(8)  float2 lds_mz[4][32];   // 1KB (m, Z) merge
    __shared__ float lds_rcs[NAGENTS], lds_rb[NAGENTS], lds_cw[NAGENTS];
    __shared__ float lds_ab;

    const int u = threadIdx.x;    // 0..255
    const int lane = u & 63;
    const int wave = u >> 6;      // 0..3
    const int c = u & 31;         // float4 column: n = c>>2, item-quad = c&3
    const int n = c >> 2;
    const int su = u >> 5;        // 0..7: row subset (s = 8k + su)
    const size_t bb_ = (size_t)blockIdx.x;

    float* out_choice = out;                                  // B*257
    float* out_item   = out + (size_t)Bsz * SFULL;            // B*128
    float* out_pay    = out_item + (size_t)Bsz * NM;          // 8*B
    float* out_all    = out_pay + (size_t)NAGENTS * Bsz;      // B*257*128
    f32x4* out_all4   = (f32x4*)out_all + bb_ * 8224;
    const f32x4* src4 = (const f32x4*)allocs + bb_ * 8192;

    const float temp = tempp[0];
    lds_bb[u] = bvec[bb_ * MENU + u];                    // stage b (256 = blockDim)
    const float4 q4 = ((const float4*)(bids + bb_ * NM))[c];   // L1 broadcast
    const float w_n = wvec[bb_ * NAGENTS + n];
    BAR();   // bb staged

    // ---- pass 1: single streaming pass over the payload ----
    float m_r = -1e30f, Z_r = 0.f;
    float4 acc = make_float4(0.f, 0.f, 0.f, 0.f);
#pragma unroll
    for (int g = 0; g < 4; ++g) {
        f32x4 buf[8];
#pragma unroll
        for (int j = 0; j < 8; ++j)
            buf[j] = src4[(((g << 3) + j) << 8) + u];
#pragma unroll
        for (int j = 0; j < 8; ++j)
            out_all4[(((g << 3) + j) << 8) + u] = buf[j];
#pragma unroll
        for (int j = 0; j < 8; ++j) {
            const int s = (((g << 3) + j) << 3) + su;
            float util = buf[j][0]*q4.x + buf[j][1]*q4.y
                       + buf[j][2]*q4.z + buf[j][3]*q4.w;
            util += __shfl_xor(util, 1);
            util += __shfl_xor(util, 2);           // full item-dot for (s,n)
            float pwv = w_n * util;
            if ((u & 3) == 0) lds_pwT[(n << 8) + (s ^ (n << 2))] = pwv;
            float t = pwv;
            t += __shfl_xor(t, 4);
            t += __shfl_xor(t, 8);
            t += __shfl_xor(t, 16);                // total welfare, all lanes
            if (c == 0) lds_tot[s] = t;
            // online softmax accumulate for item_allocation
            float x = (t + lds_bb[s]) * temp;
            float mn = fmaxf(m_r, x);
            float sc = __expf(m_r - mn);           // 1.0 when no new max
            float p  = __expf(x - mn);
            Z_r = Z_r * sc + p;
            acc.x = acc.x * sc + p * buf[j][0];
            acc.y = acc.y * sc + p * buf[j][1];
            acc.z = acc.z * sc + p * buf[j][2];
            acc.w = acc.w * sc + p * buf[j][3];
            m_r = mn;
        }
    }
    if (u < 32) {
        f32x4 z4 = {0.f, 0.f, 0.f, 0.f};
        out_all4[8192 + u] = z4;                   // null row
    }

    // pair-merge su <-> su^1 (halves of each wave)
    {
        float mo = __shfl_xor(m_r, 32);
        float Zo = __shfl_xor(Z_r, 32);
        float ax = __shfl_xor(acc.x, 32), ay = __shfl_xor(acc.y, 32);
        float az = __shfl_xor(acc.z, 32), aw = __shfl_xor(acc.w, 32);
        float mn = fmaxf(m_r, mo);
        float s0 = __expf(m_r - mn), s1 = __expf(mo - mn);
        Z_r = Z_r * s0 + Zo * s1;
        acc.x = acc.x * s0 + ax * s1;
        acc.y = acc.y * s0 + ay * s1;
        acc.z = acc.z * s0 + az * s1;
        acc.w = acc.w * s0 + aw * s1;
        if (lane < 32) {
            lds_accs[wave][c] = acc;
            lds_mz[wave][c] = make_float2(mn, Z_r);
        }
    }
    BAR();   // b1: pwT/tot/accs ready

    // ---- softmax tasks: t=0 full, t=1..8 leave-one-out (i=t-1); 4 waves ----
    for (int t = wave; t < 9; t += 4) {
        if (t == 0) {
            float xs[4], bl[4], es[4];
            float mx = -1e30f;
#pragma unroll
            for (int c4 = 0; c4 < 4; ++c4) {
                int v = (c4 << 6) | lane;
                bl[c4] = lds_bb[v];
                float x = (lds_tot[v] + bl[c4]) * temp;
                xs[c4] = x; mx = fmaxf(mx, x);
            }
            mx = fmaxf(wredmax(mx), 0.f);          // null entry x=0
            float se = 0.f, sab = 0.f;
#pragma unroll
            for (int c4 = 0; c4 < 4; ++c4) {
                es[c4] = __expf(xs[c4] - mx);
                se += es[c4]; sab += es[c4] * bl[c4];
            }
            float en = __expf(-mx);
            se = wredsum(se) + en;
            sab = wredsum(sab);
            float inv = 1.f / se;
#pragma unroll
            for (int c4 = 0; c4 < 4; ++c4) {
                int v = (c4 << 6) | lane;
                float chv = es[c4] * inv;
                lds_ch[v] = chv;
                out_choice[bb_ * SFULL + v] = chv;
            }
            if (lane == 0) {
                float chn = en * inv;
                lds_ch[MENU] = chn;
                out_choice[bb_ * SFULL + MENU] = chn;
                lds_ab = sab * inv;
            }
        } else {
            const int i = t - 1;
            float xs[4], trs[4], bl[4];
            float mx = -1e30f;
#pragma unroll
            for (int c4 = 0; c4 < 4; ++c4) {
                int v = (c4 << 6) | lane;
                bl[c4] = lds_bb[v];
                float tr = lds_tot[v] - lds_pwT[(i << 8) + (v ^ (i << 2))];
                trs[c4] = tr;
                float x = (tr + bl[c4]) * temp;
                xs[c4] = x; mx = fmaxf(mx, x);
            }
            mx = fmaxf(wredmax(mx), 0.f);
            float se = 0.f, s1 = 0.f, s2 = 0.f;
#pragma unroll
            for (int c4 = 0; c4 < 4; ++c4) {
                float e = __expf(xs[c4] - mx);
                se += e; s1 += e * trs[c4]; s2 += e * bl[c4];
            }
            se = wredsum(se) + __expf(-mx);
            s1 = wredsum(s1);
            s2 = wredsum(s2);
            if (lane == 0) { lds_rcs[i] = s1 / se; lds_rb[i] = s2 / se; }
        }
    }
    BAR();   // b2: ch/rcs/rb/ab ready

    // ---- chosen welfare (2 agents per wave) ----
    for (int i = wave; i < NAGENTS; i += 4) {
        float cwv = 0.f;
#pragma unroll
        for (int c4 = 0; c4 < 4; ++c4) {
            int v = (c4 << 6) | lane;
            cwv += lds_ch[v] * lds_pwT[(i << 8) + (v ^ (i << 2))];
        }
        cwv = wredsum(cwv);
        if (lane == 0) lds_cw[i] = cwv;
    }
    // ---- item_allocation: final cross-wave merge + null + normalize ----
    if (u < 32) {
        float4 A = lds_accs[0][u];
        float2 mz = lds_mz[0][u];
        float M = mz.x, Z = mz.y;
#pragma unroll
        for (int j = 1; j < 4; ++j) {
            float4 Aj = lds_accs[j][u];
            float2 mzj = lds_mz[j][u];
            float mn = fmaxf(M, mzj.x);
            float s0 = __expf(M - mn), s1 = __expf(mzj.x - mn);
            Z = Z * s0 + mzj.y * s1;
            A.x = A.x * s0 + Aj.x * s1;
            A.y = A.y * s0 + Aj.y * s1;
            A.z = A.z * s0 + Aj.z * s1;
            A.w = A.w * s0 + Aj.w * s1;
            M = mn;
        }
        float mn = fmaxf(M, 0.f);                  // null entry
        float s0 = __expf(M - mn);
        Z = Z * s0 + __expf(-mn);
        float inv = 1.f / Z;
        s0 *= inv;
        ((float4*)(out_item + bb_ * NM))[u] =
            make_float4(A.x * s0, A.y * s0, A.z * s0, A.w * s0);
    }
    BAR();   // b3: cw ready

    // ---- payments, layout (n, B) ----
    if (u < NAGENTS) {
        float ctot = 0.f;
#pragma unroll
        for (int k = 0; k < NAGENTS; ++k) ctot += lds_cw[k];
        float pay = (lds_rcs[u] + lds_rb[u] - (ctot - lds_cw[u]) - lds_ab)
                    / wvec[bb_ * NAGENTS + u];
        out_pay[(size_t)u * Bsz + bb_] = pay;
    }
}

extern "C" void kernel_launch(void* const* d_in, const int* in_sizes, int n_in,
                              void* d_out, int out_size, void* d_ws, size_t ws_size,
                              hipStream_t stream) {
    const float* bids   = (const float*)d_in[0];
    const float* allocs = (const float*)d_in[1];
    const float* wvec   = (const float*)d_in[2];
    const float* bvec   = (const float*)d_in[3];
    const float* tempp  = (const float*)d_in[4];
    float* out = (float*)d_out;
    const int Bsz = in_sizes[0] / NM;          // 4096
    cama_kernel<<<Bsz, 256, 0, stream>>>(bids, allocs, wvec, bvec, tempp,
                                         out, Bsz);
}

// Round 14
// 236.751 us; speedup vs baseline: 2.0643x; 2.0643x over previous
//
#include <hip/hip_runtime.h>

#define NAGENTS 8
#define NM 128          // NAGENTS*MITEMS
#define MENU 256
#define SFULL 257       // MENU + null entry

typedef float f32x4 __attribute__((ext_vector_type(4)));

// Raw barrier: wait LDS ops only (no vmcnt drain — copy-out stores and any
// in-flight loads keep flying across phases).
#define BAR() asm volatile("s_waitcnt lgkmcnt(0)\n\ts_barrier" ::: "memory")

__device__ __forceinline__ float wredmax(float v) {
#pragma unroll
    for (int o = 32; o; o >>= 1) v = fmaxf(v, __shfl_xor(v, o));
    return v;
}
__device__ __forceinline__ float wredsum(float v) {
#pragma unroll
    for (int o = 32; o; o >>= 1) v += __shfl_xor(v, o);
    return v;
}

// 256 threads/block, one auction per block, 8 blocks/CU (32 waves/CU).
// R7 structure (best measured 235us): per-chunk load -> store -> compute
// interleave with PLAIN cached float4s. R8/R13 proved batched issue causes
// ~2x write amplification (partial-line RFO at L2) — do NOT batch.
// Online-softmax folds item_allocation into the single streaming pass;
// defer-max (THR=8) removes the per-chunk rescale from the common path.
__global__ __launch_bounds__(256, 8) void cama_kernel(
    const float* __restrict__ bids,   // B,8,16
    const float* __restrict__ allocs, // B,256,8,16
    const float* __restrict__ wvec,   // B,8
    const float* __restrict__ bvec,   // B,256
    const float* __restrict__ tempp,  // 1
    float* __restrict__ out, int Bsz)
{
    __shared__ float lds_pwT[NAGENTS * MENU];        // 8KB, [n][s^(n<<2)]
    __shared__ float lds_tot[MENU];                  // 1KB
    __shared__ float lds_bb[MENU];                   // 1KB raw b
    __shared__ float lds_bbt[MENU];                  // 1KB b*temp
    __shared__ float lds_ch[SFULL];
    __shared__ __align__(16) float4 lds_accs[4][32]; // 2KB online-acc merge
    __shared__ __align__(8)  float2 lds_mz[4][32];   // 1KB (m, Z) merge
    __shared__ float lds_rcs[NAGENTS], lds_rb[NAGENTS], lds_cw[NAGENTS];
    __shared__ float lds_ab;

    const int u = threadIdx.x;    // 0..255
    const int lane = u & 63;
    const int wave = u >> 6;      // 0..3
    const int c = u & 31;         // float4 column: n = c>>2, item-quad = c&3
    const int n = c >> 2;
    const int su = u >> 5;        // 0..7: row subset (s = 8k + su)
    const size_t bb_ = (size_t)blockIdx.x;

    float* out_choice = out;                                  // B*257
    float* out_item   = out + (size_t)Bsz * SFULL;            // B*128
    float* out_pay    = out_item + (size_t)Bsz * NM;          // 8*B
    float* out_all    = out_pay + (size_t)NAGENTS * Bsz;      // B*257*128
    f32x4* out_all4   = (f32x4*)out_all + bb_ * 8224;
    const f32x4* src4 = (const f32x4*)allocs + bb_ * 8192;

    const float temp = tempp[0];
    {
        float bv = bvec[bb_ * MENU + u];
        lds_bb[u]  = bv;                             // stage b (256 = blockDim)
        lds_bbt[u] = bv * temp;
    }
    const float4 q4 = ((const float4*)(bids + bb_ * NM))[c];   // L1 broadcast
    const float w_n = wvec[bb_ * NAGENTS + n];
    BAR();   // bb staged

    // ---- pass 1: single streaming pass, per-chunk interleave ----
    float m_r = -1e30f, Z_r = 0.f;
    float4 acc = make_float4(0.f, 0.f, 0.f, 0.f);
#pragma unroll 4
    for (int k = 0; k < 32; ++k) {
        const int idx = (k << 8) + u;              // lane-contiguous float4
        f32x4 a4 = src4[idx];
        out_all4[idx] = a4;                        // copy-out (never re-read)
        const int s = (k << 3) + su;
        float util = a4[0]*q4.x + a4[1]*q4.y + a4[2]*q4.z + a4[3]*q4.w;
        util += __shfl_xor(util, 1);
        util += __shfl_xor(util, 2);               // full item-dot for (s,n)
        float pwv = w_n * util;
        if ((u & 3) == 0) lds_pwT[(n << 8) + (s ^ (n << 2))] = pwv;
        float t = pwv;
        t += __shfl_xor(t, 4);
        t += __shfl_xor(t, 8);
        t += __shfl_xor(t, 16);                    // total welfare, all lanes
        if (c == 0) lds_tot[s] = t;
        // online softmax accumulate (defer-max, THR=8)
        float x = fmaf(t, temp, lds_bbt[s]);
        if (x > m_r + 8.f) {                       // rare after warmup
            float sc = __expf(m_r - x);
            Z_r *= sc;
            acc.x *= sc; acc.y *= sc; acc.z *= sc; acc.w *= sc;
            m_r = x;
        }
        float p = __expf(x - m_r);                 // bounded by e^8
        Z_r += p;
        acc.x = fmaf(p, a4[0], acc.x);
        acc.y = fmaf(p, a4[1], acc.y);
        acc.z = fmaf(p, a4[2], acc.z);
        acc.w = fmaf(p, a4[3], acc.w);
    }
    if (u < 32) {
        f32x4 z4 = {0.f, 0.f, 0.f, 0.f};
        out_all4[8192 + u] = z4;                   // null row
    }

    // pair-merge su <-> su^1 (halves of each wave)
    {
        float mo = __shfl_xor(m_r, 32);
        float Zo = __shfl_xor(Z_r, 32);
        float ax = __shfl_xor(acc.x, 32), ay = __shfl_xor(acc.y, 32);
        float az = __shfl_xor(acc.z, 32), aw = __shfl_xor(acc.w, 32);
        float mn = fmaxf(m_r, mo);
        float s0 = __expf(m_r - mn), s1 = __expf(mo - mn);
        Z_r = Z_r * s0 + Zo * s1;
        acc.x = acc.x * s0 + ax * s1;
        acc.y = acc.y * s0 + ay * s1;
        acc.z = acc.z * s0 + az * s1;
        acc.w = acc.w * s0 + aw * s1;
        if (lane < 32) {
            lds_accs[wave][c] = acc;
            lds_mz[wave][c] = make_float2(mn, Z_r);
        }
    }
    BAR();   // b1: pwT/tot/accs ready

    // ---- softmax tasks: t=0 full, t=1..8 leave-one-out (i=t-1); 4 waves ----
    for (int t = wave; t < 9; t += 4) {
        if (t == 0) {
            float xs[4], bl[4], es[4];
            float mx = -1e30f;
#pragma unroll
            for (int c4 = 0; c4 < 4; ++c4) {
                int v = (c4 << 6) | lane;
                bl[c4] = lds_bb[v];
                float x = (lds_tot[v] + bl[c4]) * temp;
                xs[c4] = x; mx = fmaxf(mx, x);
            }
            mx = fmaxf(wredmax(mx), 0.f);          // null entry x=0
            float se = 0.f, sab = 0.f;
#pragma unroll
            for (int c4 = 0; c4 < 4; ++c4) {
                es[c4] = __expf(xs[c4] - mx);
                se += es[c4]; sab += es[c4] * bl[c4];
            }
            float en = __expf(-mx);
            se = wredsum(se) + en;
            sab = wredsum(sab);
            float inv = 1.f / se;
#pragma unroll
            for (int c4 = 0; c4 < 4; ++c4) {
                int v = (c4 << 6) | lane;
                float chv = es[c4] * inv;
                lds_ch[v] = chv;
                out_choice[bb_ * SFULL + v] = chv;
            }
            if (lane == 0) {
                float chn = en * inv;
                lds_ch[MENU] = chn;
                out_choice[bb_ * SFULL + MENU] = chn;
                lds_ab = sab * inv;
            }
        } else {
            const int i = t - 1;
            float xs[4], trs[4], bl[4];
            float mx = -1e30f;
#pragma unroll
            for (int c4 = 0; c4 < 4; ++c4) {
                int v = (c4 << 6) | lane;
                bl[c4] = lds_bb[v];
                float tr = lds_tot[v] - lds_pwT[(i << 8) + (v ^ (i << 2))];
                trs[c4] = tr;
                float x = (tr + bl[c4]) * temp;
                xs[c4] = x; mx = fmaxf(mx, x);
            }
            mx = fmaxf(wredmax(mx), 0.f);
            float se = 0.f, s1 = 0.f, s2 = 0.f;
#pragma unroll
            for (int c4 = 0; c4 < 4; ++c4) {
                float e = __expf(xs[c4] - mx);
                se += e; s1 += e * trs[c4]; s2 += e * bl[c4];
            }
            se = wredsum(se) + __expf(-mx);
            s1 = wredsum(s1);
            s2 = wredsum(s2);
            if (lane == 0) { lds_rcs[i] = s1 / se; lds_rb[i] = s2 / se; }
        }
    }
    BAR();   // b2: ch/rcs/rb/ab ready

    // ---- chosen welfare (2 agents per wave) ----
    for (int i = wave; i < NAGENTS; i += 4) {
        float cwv = 0.f;
#pragma unroll
        for (int c4 = 0; c4 < 4; ++c4) {
            int v = (c4 << 6) | lane;
            cwv += lds_ch[v] * lds_pwT[(i << 8) + (v ^ (i << 2))];
        }
        cwv = wredsum(cwv);
        if (lane == 0) lds_cw[i] = cwv;
    }
    // ---- item_allocation: final cross-wave merge + null + normalize ----
    if (u < 32) {
        float4 A = lds_accs[0][u];
        float2 mz = lds_mz[0][u];
        float M = mz.x, Z = mz.y;
#pragma unroll
        for (int j = 1; j < 4; ++j) {
            float4 Aj = lds_accs[j][u];
            float2 mzj = lds_mz[j][u];
            float mn = fmaxf(M, mzj.x);
            float s0 = __expf(M - mn), s1 = __expf(mzj.x - mn);
            Z = Z * s0 + mzj.y * s1;
            A.x = A.x * s0 + Aj.x * s1;
            A.y = A.y * s0 + Aj.y * s1;
            A.z = A.z * s0 + Aj.z * s1;
            A.w = A.w * s0 + Aj.w * s1;
            M = mn;
        }
        float mn = fmaxf(M, 0.f);                  // null entry
        float s0 = __expf(M - mn);
        Z = Z * s0 + __expf(-mn);
        float inv = 1.f / Z;
        s0 *= inv;
        ((float4*)(out_item + bb_ * NM))[u] =
            make_float4(A.x * s0, A.y * s0, A.z * s0, A.w * s0);
    }
    BAR();   // b3: cw ready

    // ---- payments, layout (n, B) ----
    if (u < NAGENTS) {
        float ctot = 0.f;
#pragma unroll
        for (int k = 0; k < NAGENTS; ++k) ctot += lds_cw[k];
        float pay = (lds_rcs[u] + lds_rb[u] - (ctot - lds_cw[u]) - lds_ab)
                    / wvec[bb_ * NAGENTS + u];
        out_pay[(size_t)u * Bsz + bb_] = pay;
    }
}

extern "C" void kernel_launch(void* const* d_in, const int* in_sizes, int n_in,
                              void* d_out, int out_size, void* d_ws, size_t ws_size,
                              hipStream_t stream) {
    const float* bids   = (const float*)d_in[0];
    const float* allocs = (const float*)d_in[1];
    const float* wvec   = (const float*)d_in[2];
    const float* bvec   = (const float*)d_in[3];
    const float* tempp  = (const float*)d_in[4];
    float* out = (float*)d_out;
    const int Bsz = in_sizes[0] / NM;          // 4096
    cama_kernel<<<Bsz, 256, 0, stream>>>(bids, allocs, wvec, bvec, tempp,
                                         out, Bsz);
}

// Round 15
// 233.718 us; speedup vs baseline: 2.0911x; 1.0130x over previous
//
#include <hip/hip_runtime.h>

#define NAGENTS 8
#define NM 128          // NAGENTS*MITEMS
#define MENU 256
#define SFULL 257       // MENU + null entry

typedef float f32x4 __attribute__((ext_vector_type(4)));

// Raw barrier: wait LDS ops only (no vmcnt drain — copy-out stores and any
// in-flight loads keep flying across phases).
#define BAR() asm volatile("s_waitcnt lgkmcnt(0)\n\ts_barrier" ::: "memory")

// 256 threads/block, one auction per block, 8 blocks/CU (32 waves/CU).
// FULLY-ONLINE: the single streaming pass computes, per thread, online-softmax
// states for (a) the full menu softmax (M1,Z1) + Sab (alloc_b) + Scw (chosen
// welfare, own agent) + A4 (item_allocation) and (b) the leave-one-out softmax
// for its own agent (M2,Z2,S1,S2). The post-stream tail is just two tiny merge
// stages — no pwT, no 9-softmax phase — so co-resident blocks return to
// streaming almost immediately (HBM stays fed).
// Per-chunk interleave load->store->compute (R8/R13: batching causes ~2x write
// amplification; plain cached float4s only).
__global__ __launch_bounds__(256, 8) void cama_kernel(
    const float* __restrict__ bids,   // B,8,16
    const float* __restrict__ allocs, // B,256,8,16
    const float* __restrict__ wvec,   // B,8
    const float* __restrict__ bvec,   // B,256
    const float* __restrict__ tempp,  // 1
    float* __restrict__ out, int Bsz)
{
    __shared__ float lds_tot[MENU];                  // 1KB
    __shared__ float lds_bb[MENU];                   // 1KB
    __shared__ __align__(16) float4 lds_accs[4][32]; // 2KB item partials
    __shared__ __align__(16) float4 lds_w1[4];       // per-wave (M1,Z1,Sab,-)
    __shared__ __align__(16) float4 lds_loo[4][8];   // per-wave (M2,Z2,S1,S2)
    __shared__ float lds_scw[4][8];                  // per-wave Scw[n]
    __shared__ float lds_rcs[NAGENTS], lds_rb[NAGENTS], lds_cw[NAGENTS];
    __shared__ float lds_ab;
    __shared__ float2 lds_mzf;                       // (M1f, 1/Z1f)

    const int u = threadIdx.x;    // 0..255
    const int lane = u & 63;
    const int wave = u >> 6;      // 0..3
    const int c = u & 31;         // n = c>>2, item-quad mq = u&3
    const int n = c >> 2;
    const int mq = u & 3;
    const int su = u >> 5;        // s = 8k + su
    const size_t bb_ = (size_t)blockIdx.x;

    float* out_choice = out;                                  // B*257
    float* out_item   = out + (size_t)Bsz * SFULL;            // B*128
    float* out_pay    = out_item + (size_t)Bsz * NM;          // 8*B
    float* out_all    = out_pay + (size_t)NAGENTS * Bsz;      // B*257*128
    f32x4* out_all4   = (f32x4*)out_all + bb_ * 8224;
    const f32x4* src4 = (const f32x4*)allocs + bb_ * 8192;

    const float temp = tempp[0];
    lds_bb[u] = bvec[bb_ * MENU + u];                    // 256 = blockDim
    const float4 q4 = ((const float4*)(bids + bb_ * NM))[c];   // L1 broadcast
    const float w_n = wvec[bb_ * NAGENTS + n];
    BAR();   // bb staged

    // online states
    float M1 = -1e30f, Z1 = 0.f, Sab = 0.f, Scw = 0.f;
    float4 A = make_float4(0.f, 0.f, 0.f, 0.f);
    float M2 = -1e30f, Z2 = 0.f, S1 = 0.f, S2 = 0.f;

    // ---- pass 1: single streaming pass, per-chunk interleave ----
#pragma unroll 4
    for (int k = 0; k < 32; ++k) {
        const int idx = (k << 8) + u;              // lane-contiguous float4
        f32x4 a4 = src4[idx];
        out_all4[idx] = a4;                        // copy-out (never re-read)
        const int s = (k << 3) + su;
        const float bbs = lds_bb[s];
        float util = a4[0]*q4.x + a4[1]*q4.y + a4[2]*q4.z + a4[3]*q4.w;
        util += __shfl_xor(util, 1);
        util += __shfl_xor(util, 2);               // item-dot for (s,n)
        float pwv = w_n * util;
        float t = pwv;
        t += __shfl_xor(t, 4);
        t += __shfl_xor(t, 8);
        t += __shfl_xor(t, 16);                    // tot[s], all lanes
        if (c == 0) lds_tot[s] = t;
        // full-softmax family
        float x = (t + bbs) * temp;
        float mn = fmaxf(M1, x);
        float sc = __expf(M1 - mn);
        float p  = __expf(x - mn);
        Z1  = Z1*sc + p;
        A.x = A.x*sc + p*a4[0];
        A.y = A.y*sc + p*a4[1];
        A.z = A.z*sc + p*a4[2];
        A.w = A.w*sc + p*a4[3];
        Sab = Sab*sc + p*bbs;
        Scw = Scw*sc + p*pwv;
        M1 = mn;
        // leave-one-out family (own agent n)
        float tr = t - pwv;
        float x2 = (tr + bbs) * temp;
        float mn2 = fmaxf(M2, x2);
        float sc2 = __expf(M2 - mn2);
        float p2  = __expf(x2 - mn2);
        Z2 = Z2*sc2 + p2;
        S1 = S1*sc2 + p2*tr;
        S2 = S2*sc2 + p2*bbs;
        M2 = mn2;
    }
    if (u < 32) {
        f32x4 z4 = {0.f, 0.f, 0.f, 0.f};
        out_all4[8192 + u] = z4;                   // null row of the copy
    }

    // ---- su-pair merge (lane <-> lane^32), then per-wave partials to LDS ----
    {
        float Mo = __shfl_xor(M1, 32), Zo = __shfl_xor(Z1, 32);
        float Sabo = __shfl_xor(Sab, 32), Scwo = __shfl_xor(Scw, 32);
        float ax = __shfl_xor(A.x, 32), ay = __shfl_xor(A.y, 32);
        float az = __shfl_xor(A.z, 32), aw = __shfl_xor(A.w, 32);
        float mn = fmaxf(M1, Mo);
        float s0 = __expf(M1 - mn), s1 = __expf(Mo - mn);
        Z1  = Z1*s0  + Zo*s1;
        Sab = Sab*s0 + Sabo*s1;
        Scw = Scw*s0 + Scwo*s1;
        A.x = A.x*s0 + ax*s1;  A.y = A.y*s0 + ay*s1;
        A.z = A.z*s0 + az*s1;  A.w = A.w*s0 + aw*s1;
        M1 = mn;

        float Mo2 = __shfl_xor(M2, 32), Zo2 = __shfl_xor(Z2, 32);
        float S1o = __shfl_xor(S1, 32), S2o = __shfl_xor(S2, 32);
        float mn2 = fmaxf(M2, Mo2);
        float t0 = __expf(M2 - mn2), t1 = __expf(Mo2 - mn2);
        Z2 = Z2*t0 + Zo2*t1;
        S1 = S1*t0 + S1o*t1;
        S2 = S2*t0 + S2o*t1;
        M2 = mn2;

        if (lane < 32) {
            lds_accs[wave][c] = make_float4(A.x, A.y, A.z, A.w);
            if (c == 0) lds_w1[wave] = make_float4(M1, Z1, Sab, 0.f);
            if (mq == 0) {
                lds_scw[wave][n] = Scw;
                lds_loo[wave][n] = make_float4(M2, Z2, S1, S2);
            }
        }
    }
    BAR();   // b1: tot + all per-wave partials ready

    // ---- stage A: final merges (one wave busy, others idle briefly) ----
    if (u < 32) {
        // item_allocation (+ u==0: ab, mzf)
        float4 w1 = lds_w1[0];
        float Mm = w1.x, Zm = w1.y, Sabm = w1.z;
        float4 Am = lds_accs[0][u];
#pragma unroll
        for (int j = 1; j < 4; ++j) {
            float4 wj = lds_w1[j];
            float4 Aj = lds_accs[j][u];
            float mn = fmaxf(Mm, wj.x);
            float s0 = __expf(Mm - mn), s1 = __expf(wj.x - mn);
            Zm   = Zm*s0   + wj.y*s1;
            Sabm = Sabm*s0 + wj.z*s1;
            Am.x = Am.x*s0 + Aj.x*s1;  Am.y = Am.y*s0 + Aj.y*s1;
            Am.z = Am.z*s0 + Aj.z*s1;  Am.w = Am.w*s0 + Aj.w*s1;
            Mm = mn;
        }
        float M1f = fmaxf(Mm, 0.f);                // null entry x=0
        float s0 = __expf(Mm - M1f);
        float Z1f = Zm*s0 + __expf(-M1f);
        float inv = 1.f / Z1f;
        float sf = s0 * inv;
        ((float4*)(out_item + bb_ * NM))[u] =
            make_float4(Am.x*sf, Am.y*sf, Am.z*sf, Am.w*sf);
        if (u == 0) {
            lds_ab = Sabm * sf;
            lds_mzf = make_float2(M1f, inv);
        }
    } else if (u < 40) {
        // LOO finalize for agent i
        const int i = u - 32;
        float4 L = lds_loo[0][i];
        float Mm = L.x, Zm = L.y, S1m = L.z, S2m = L.w;
#pragma unroll
        for (int j = 1; j < 4; ++j) {
            float4 Lj = lds_loo[j][i];
            float mn = fmaxf(Mm, Lj.x);
            float s0 = __expf(Mm - mn), s1 = __expf(Lj.x - mn);
            Zm  = Zm*s0  + Lj.y*s1;
            S1m = S1m*s0 + Lj.z*s1;
            S2m = S2m*s0 + Lj.w*s1;
            Mm = mn;
        }
        float M2f = fmaxf(Mm, 0.f);                // null: tr=0, b=0
        float s0 = __expf(Mm - M2f);
        float Z2f = Zm*s0 + __expf(-M2f);
        lds_rcs[i] = S1m*s0 / Z2f;
        lds_rb[i]  = S2m*s0 / Z2f;
    } else if (u < 48) {
        // chosen-welfare finalize for agent i
        const int i = u - 40;
        float4 w1 = lds_w1[0];
        float Mm = w1.x, Zm = w1.y;
        float Sm = lds_scw[0][i];
#pragma unroll
        for (int j = 1; j < 4; ++j) {
            float4 wj = lds_w1[j];
            float mn = fmaxf(Mm, wj.x);
            float s0 = __expf(Mm - mn), s1 = __expf(wj.x - mn);
            Zm = Zm*s0 + wj.y*s1;
            Sm = Sm*s0 + lds_scw[j][i]*s1;
            Mm = mn;
        }
        float M1f = fmaxf(Mm, 0.f);
        float s0 = __expf(Mm - M1f);
        float Z1f = Zm*s0 + __expf(-M1f);
        lds_cw[i] = Sm*s0 / Z1f;
    }
    BAR();   // b2: ab/mzf/rcs/rb/cw ready

    // ---- stage B: out_choice (all threads) + payments (8 threads) ----
    {
        float2 mzf = lds_mzf;
        float x = (lds_tot[u] + lds_bb[u]) * temp;
        out_choice[bb_ * SFULL + u] = __expf(x - mzf.x) * mzf.y;
        if (u == 0)
            out_choice[bb_ * SFULL + MENU] = __expf(-mzf.x) * mzf.y;
    }
    if (u < NAGENTS) {
        float ctot = 0.f;
#pragma unroll
        for (int k = 0; k < NAGENTS; ++k) ctot += lds_cw[k];
        float pay = (lds_rcs[u] + lds_rb[u] - (ctot - lds_cw[u]) - lds_ab)
                    / wvec[bb_ * NAGENTS + u];
        out_pay[(size_t)u * Bsz + bb_] = pay;
    }
}

extern "C" void kernel_launch(void* const* d_in, const int* in_sizes, int n_in,
                              void* d_out, int out_size, void* d_ws, size_t ws_size,
                              hipStream_t stream) {
    const float* bids   = (const float*)d_in[0];
    const float* allocs = (const float*)d_in[1];
    const float* wvec   = (const float*)d_in[2];
    const float* bvec   = (const float*)d_in[3];
    const float* tempp  = (const float*)d_in[4];
    float* out = (float*)d_out;
    const int Bsz = in_sizes[0] / NM;          // 4096
    cama_kernel<<<Bsz, 256, 0, stream>>>(bids, allocs, wvec, bvec, tempp,
                                         out, Bsz);
}